// Round 4
// baseline (351.617 us; speedup 1.0000x reference)
//
#include <hip/hip_runtime.h>

// ---------------- types / helpers ----------------
typedef __attribute__((ext_vector_type(8))) short short8;   // 8 bf16 = 4 VGPRs (MFMA A/B frag)
typedef __attribute__((ext_vector_type(4))) float f32x4;    // MFMA C/D frag
typedef __attribute__((ext_vector_type(2))) unsigned uint2v;

#define MFMA(a, b, c) __builtin_amdgcn_mfma_f32_16x16x32_bf16((a), (b), (c), 0, 0, 0)

__device__ __forceinline__ short f2bf(float f) {   // RNE float->bf16 (bit pattern as short)
    union { float f; unsigned u; } v; v.f = f;
    unsigned r = v.u + 0x7fffu + ((v.u >> 16) & 1u);
    return (short)(r >> 16);
}
__device__ __forceinline__ float bf2f(short s) {
    union { unsigned u; float f; } v; v.u = ((unsigned)(unsigned short)s) << 16; return v.f;
}
// pack two floats -> 2 bf16 in one u32 (pure integer ops; verified in round 3)
__device__ __forceinline__ unsigned pkbf(float lo, float hi) {
    return (unsigned)(unsigned short)f2bf(lo) | ((unsigned)(unsigned short)f2bf(hi) << 16);
}
__device__ __forceinline__ float lrelu(float v) { return (v >= 0.f) ? v : 0.01f * v; }

// ---------------- weight fp32 -> bf16 conversion (once per launch) ----------------
struct ConvArgs { const float* src[6]; int end[6]; };  // end[] in float4 units, cumulative

__global__ __launch_bounds__(256) void convert_weights_kernel(ConvArgs a, short* __restrict__ dstw) {
    int i4 = blockIdx.x * 256 + threadIdx.x;
    int seg = 0;
#pragma unroll
    for (int s = 0; s < 5; s++) seg += (i4 >= a.end[s]) ? 1 : 0;
    int base = (seg == 0) ? 0 : a.end[seg - 1];
    float4 v = ((const float4*)a.src[seg])[i4 - base];
    uint2v o = { pkbf(v.x, v.y), pkbf(v.z, v.w) };
    *(uint2v*)(dstw + (size_t)i4 * 4) = o;
}

// ---------------- precompute Gt = (Qw^T Kw)/sqrt(d) (bf16) and wvec = (qb^T Kw)/sqrt(d) ----------------
__global__ __launch_bounds__(256) void precompute_gt_kernel(
    const float* __restrict__ Q1w, const float* __restrict__ K1w, const float* __restrict__ Q1b,
    const float* __restrict__ Q2w, const float* __restrict__ K2w, const float* __restrict__ Q2b,
    short* __restrict__ gt, float* __restrict__ wvec) {
    const int s  = blockIdx.x >> 5;
    const int h  = (blockIdx.x >> 3) & 3;
    const int fg = blockIdx.x & 7;
    const float* Qw = (s ? Q2w : Q1w) + (size_t)h * 16384;
    const float* Kw = (s ? K2w : K1w) + (size_t)h * 16384;
    const float* qb = (s ? Q2b : Q1b) + h * 128;
    const int f  = fg * 16 + (threadIdx.x >> 4);
    const int e0 = (threadIdx.x & 15) * 8;
    float acc[8] = {0.f, 0.f, 0.f, 0.f, 0.f, 0.f, 0.f, 0.f};
    float accw = 0.f;
#pragma unroll 4
    for (int c = 0; c < 128; c++) {
        float kv = Kw[c * 128 + f];
        accw = fmaf(qb[c], kv, accw);
        float4 a0 = *(const float4*)(Qw + c * 128 + e0);
        float4 a1 = *(const float4*)(Qw + c * 128 + e0 + 4);
        acc[0] = fmaf(kv, a0.x, acc[0]); acc[1] = fmaf(kv, a0.y, acc[1]);
        acc[2] = fmaf(kv, a0.z, acc[2]); acc[3] = fmaf(kv, a0.w, acc[3]);
        acc[4] = fmaf(kv, a1.x, acc[4]); acc[5] = fmaf(kv, a1.y, acc[5]);
        acc[6] = fmaf(kv, a1.z, acc[6]); acc[7] = fmaf(kv, a1.w, acc[7]);
    }
    const float scale = 0.08838834764831845f;     // 1/sqrt(128)
    short8 o = { f2bf(acc[0] * scale), f2bf(acc[1] * scale), f2bf(acc[2] * scale), f2bf(acc[3] * scale),
                 f2bf(acc[4] * scale), f2bf(acc[5] * scale), f2bf(acc[6] * scale), f2bf(acc[7] * scale) };
    *(short8*)(gt + ((size_t)((s * 4 + h) * 128 + f)) * 128 + e0) = o;
    if (e0 == 0) wvec[(s * 4 + h) * 128 + f] = accw * scale;
}

// ---------------- fused attention stage (row-split, 3 barriers, 4 blocks/CU) ----------------
// Wave wv owns output rows wv*16..+15 end-to-end. X read straight from global (no staging).
// LDS (short offsets):
//   T  [64][136] @0      (W [64][136] overlays row-for-row after logits -> no cross-wave hazard)
//   SE [64][136] @8704
//   VT [32][72]  @17408
//   CB float[64] @19712
// Total 39,680 B -> 4 blocks/CU (both stages).
template<int IN, bool XF32>
__global__ __launch_bounds__(256, 4) void attn_stage_kernel(
    const void* __restrict__ xin,                      // [512][64][IN] fp32 (stage1) or bf16 (stage2)
    const short* __restrict__ Ew, const float* __restrict__ Eb,   // Ew bf16 [4][128][IN]
    const short* __restrict__ Gt, const float* __restrict__ wvec, // [4][128][128] bf16, [4][128] f32
    const short* __restrict__ Vw, const float* __restrict__ Vb,   // [4][32][128]
    float* __restrict__ w_out,                          // [4][512][64][64] fp32
    short* __restrict__ x_out)                          // [512][64][128] bf16
{
    constexpr int OFF_T  = 0;
    constexpr int OFF_SE = 8704;
    constexpr int OFF_VT = 17408;
    constexpr int OFF_CB = 19712;
    __shared__ short sm[19840];   // 39,680 B

    const int tid  = threadIdx.x;
    // XCD-affinity decode: the 4 h-blocks of one b share blockIdx%8 -> same XCD L2.
    const int b    = blockIdx.x & 511;
    const int h    = blockIdx.x >> 9;
    const int wv   = tid >> 6;          // wave 0..3
    const int lane = tid & 63;
    const int quad = lane >> 4;
    const int l16  = lane & 15;
    const int myrow = wv * 16 + l16;    // this lane's owned output row
    constexpr int NK1 = IN / 32;

    // ---- P1: SE[myrow] = leaky(X @ Ew^T + Eb); row-split, weights streamed (L1-shared across waves) ----
    {
        const short* ewh = Ew + (size_t)h * 128 * IN;
        f32x4 acc[8];
#pragma unroll
        for (int e = 0; e < 8; e++) acc[e] = *(const f32x4*)&Eb[h * 128 + e * 16 + quad * 4];
#pragma unroll
        for (int k0i = 0; k0i < NK1; k0i++) {
            short8 xf;   // B-frag: X[myrow][k0+quad*8 .. +8]
            if constexpr (XF32) {
                const float* xp = (const float*)xin + ((size_t)b * 64 + myrow) * IN + k0i * 32 + quad * 8;
                float4 a0 = *(const float4*)xp;
                float4 a1 = *(const float4*)(xp + 4);
                union { unsigned u[4]; short8 s; } xu;
                xu.u[0] = pkbf(a0.x, a0.y); xu.u[1] = pkbf(a0.z, a0.w);
                xu.u[2] = pkbf(a1.x, a1.y); xu.u[3] = pkbf(a1.z, a1.w);
                xf = xu.s;
            } else {
                xf = *(const short8*)((const short*)xin + ((size_t)b * 64 + myrow) * IN + k0i * 32 + quad * 8);
            }
#pragma unroll
            for (int e = 0; e < 8; e++) {
                short8 ef = *(const short8*)(ewh + (size_t)(e * 16 + l16) * IN + k0i * 32 + quad * 8);
                acc[e] = MFMA(ef, xf, acc[e]);   // C[e][xrow]
            }
        }
#pragma unroll
        for (int e = 0; e < 8; e++) {
            uint2v o = { pkbf(lrelu(acc[e][0]), lrelu(acc[e][1])),
                         pkbf(lrelu(acc[e][2]), lrelu(acc[e][3])) };
            *(uint2v*)&sm[OFF_SE + myrow * 136 + e * 16 + quad * 4] = o;
        }
    }
    __syncthreads();   // B1: SE published

    // ---- P2: T[myrow] = SE[myrow]@G^T (regs->LDS); V rows; cb — all wave-private inputs ----
    {
        short8 sf[4];   // SE[myrow] frags; serve as B for T-GEMM and A for V-GEMM
#pragma unroll
        for (int k0i = 0; k0i < 4; k0i++)
            sf[k0i] = *(const short8*)&sm[OFF_SE + myrow * 136 + k0i * 32 + quad * 8];

        const short* gth = Gt + (size_t)h * 16384;
        f32x4 tacc[8];
#pragma unroll
        for (int f = 0; f < 8; f++) tacc[f] = (f32x4){0.f, 0.f, 0.f, 0.f};
        __builtin_amdgcn_s_setprio(1);
#pragma unroll
        for (int k0i = 0; k0i < 4; k0i++)
#pragma unroll
            for (int f = 0; f < 8; f++) {
                short8 gf = *(const short8*)(gth + (size_t)(f * 16 + l16) * 128 + k0i * 32 + quad * 8);
                tacc[f] = MFMA(gf, sf[k0i], tacc[f]);   // C[f][q=myrow]
            }
#pragma unroll
        for (int f = 0; f < 8; f++) {
            uint2v ot = { pkbf(tacc[f][0], tacc[f][1]), pkbf(tacc[f][2], tacc[f][3]) };
            *(uint2v*)&sm[OFF_T + myrow * 136 + f * 16 + quad * 4] = ot;
        }

        // V: C[serow][o] with A = SE[myrow] frags (reused), B = Vw rows
        const short* vwh = Vw + (size_t)h * 32 * 128;
        f32x4 vacc[2];
#pragma unroll
        for (int o = 0; o < 2; o++) { float bv = Vb[h * 32 + o * 16 + l16]; vacc[o] = (f32x4){bv, bv, bv, bv}; }
#pragma unroll
        for (int k0i = 0; k0i < 4; k0i++)
#pragma unroll
            for (int o = 0; o < 2; o++) {
                short8 vb8 = *(const short8*)(vwh + (size_t)(o * 16 + l16) * 128 + k0i * 32 + quad * 8);
                vacc[o] = MFMA(sf[k0i], vb8, vacc[o]);
            }
        __builtin_amdgcn_s_setprio(0);
#pragma unroll
        for (int o = 0; o < 2; o++) {
            uint2v ov = { pkbf(lrelu(vacc[o][0]), lrelu(vacc[o][1])),
                          pkbf(lrelu(vacc[o][2]), lrelu(vacc[o][3])) };
            *(uint2v*)&sm[OFF_VT + (o * 16 + l16) * 72 + wv * 16 + quad * 4] = ov;
        }

        // cb[k] = SE_k . wvec (own rows; row-constant softmax terms cancel)
        {
            const float* wvh = wvec + h * 128;
            const int row = wv * 16 + (lane >> 2);
            const int e0 = (lane & 3) * 32;
            float s = 0.f;
#pragma unroll
            for (int u = 0; u < 32; u += 8) {
                short8 sv = *(const short8*)&sm[OFF_SE + row * 136 + e0 + u];
                float4 w0 = *(const float4*)(wvh + e0 + u);
                float4 w1 = *(const float4*)(wvh + e0 + u + 4);
                s = fmaf(bf2f(sv[0]), w0.x, s); s = fmaf(bf2f(sv[1]), w0.y, s);
                s = fmaf(bf2f(sv[2]), w0.z, s); s = fmaf(bf2f(sv[3]), w0.w, s);
                s = fmaf(bf2f(sv[4]), w1.x, s); s = fmaf(bf2f(sv[5]), w1.y, s);
                s = fmaf(bf2f(sv[6]), w1.z, s); s = fmaf(bf2f(sv[7]), w1.w, s);
            }
            s += __shfl_xor(s, 1, 4);
            s += __shfl_xor(s, 2, 4);
            if ((lane & 3) == 0) ((float*)&sm[OFF_CB])[row] = s;
        }
    }
    __syncthreads();   // B2: T(own, drained), VT, CB published

    // ---- P3: logits C[k][q=myrow]: A = SE (all rows), B = T[myrow] ----
    f32x4 lacc[4];
#pragma unroll
    for (int jj = 0; jj < 4; jj++) lacc[jj] = (f32x4){0.f, 0.f, 0.f, 0.f};
    __builtin_amdgcn_s_setprio(1);
#pragma unroll
    for (int k0 = 0; k0 < 128; k0 += 32) {
        short8 tf = *(const short8*)&sm[OFF_T + myrow * 136 + k0 + quad * 8];
#pragma unroll
        for (int jj = 0; jj < 4; jj++) {
            short8 af = *(const short8*)&sm[OFF_SE + (jj * 16 + l16) * 136 + k0 + quad * 8];
            lacc[jj] = MFMA(af, tf, lacc[jj]);
        }
    }
    __builtin_amdgcn_s_setprio(0);

    // ---- softmax (per-lane row): W overlays own T rows; full-line NT w_out ----
    {
        const float* cbf = (const float*)&sm[OFF_CB];
#pragma unroll
        for (int jj = 0; jj < 4; jj++) {
            f32x4 cb4 = *(const f32x4*)&cbf[jj * 16 + quad * 4];
            lacc[jj] += cb4;
        }
        float m01 = fmaxf(fmaxf(lacc[0][0], lacc[0][1]), fmaxf(lacc[0][2], lacc[0][3]));
        float m23 = fmaxf(fmaxf(lacc[1][0], lacc[1][1]), fmaxf(lacc[1][2], lacc[1][3]));
        float m45 = fmaxf(fmaxf(lacc[2][0], lacc[2][1]), fmaxf(lacc[2][2], lacc[2][3]));
        float m67 = fmaxf(fmaxf(lacc[3][0], lacc[3][1]), fmaxf(lacc[3][2], lacc[3][3]));
        float m = fmaxf(fmaxf(m01, m23), fmaxf(m45, m67));
        m = fmaxf(m, __shfl_xor(m, 16, 64));
        m = fmaxf(m, __shfl_xor(m, 32, 64));
        float sum = 0.f;
#pragma unroll
        for (int jj = 0; jj < 4; jj++)
#pragma unroll
            for (int r = 0; r < 4; r++) {
                float e = __expf(lacc[jj][r] - m);   // scale pre-folded into Gt/wvec
                lacc[jj][r] = e; sum += e;
            }
        sum += __shfl_xor(sum, 16, 64);
        sum += __shfl_xor(sum, 32, 64);
        float inv = 1.0f / sum;
        float* wbase = w_out + ((size_t)(h * 512 + b)) * 4096 + (size_t)myrow * 64;
#pragma unroll
        for (int jj = 0; jj < 4; jj++) {
            f32x4 w4 = { lacc[jj][0] * inv, lacc[jj][1] * inv, lacc[jj][2] * inv, lacc[jj][3] * inv };
            uint2v o = { pkbf(w4[0], w4[1]), pkbf(w4[2], w4[3]) };
            *(uint2v*)&sm[OFF_T + myrow * 136 + jj * 16 + quad * 4] = o;   // W over own T row
            __builtin_nontemporal_store(w4, (f32x4*)(wbase + jj * 16 + quad * 4));
        }
    }
    __syncthreads();   // B3: W drained (insurance; rows are wave-private)

    // ---- P4: att C[o][q=myrow]: A = VT rows, B = W[myrow]; packed 8B x_out ----
    {
        f32x4 aacc[2]; aacc[0] = (f32x4){0.f, 0.f, 0.f, 0.f}; aacc[1] = aacc[0];
#pragma unroll
        for (int k0 = 0; k0 < 64; k0 += 32) {
            short8 wf = *(const short8*)&sm[OFF_T + myrow * 136 + k0 + quad * 8];
#pragma unroll
            for (int o = 0; o < 2; o++) {
                short8 vf = *(const short8*)&sm[OFF_VT + (o * 16 + l16) * 72 + k0 + quad * 8];
                aacc[o] = MFMA(vf, wf, aacc[o]);
            }
        }
        short* xob = x_out + (size_t)b * 8192 + (size_t)myrow * 128 + h * 32;
#pragma unroll
        for (int o = 0; o < 2; o++) {
            uint2v o8 = { pkbf(aacc[o][0], aacc[o][1]), pkbf(aacc[o][2], aacc[o][3]) };
            *(uint2v*)&xob[o * 16 + quad * 4] = o8;
        }
    }
}

// ---------------- final MLP + softmax (round-3 verified) ----------------
#define H_LD 72
__global__ __launch_bounds__(256)
void final_mlp_mfma_kernel(const short* __restrict__ x2,    // [32768][128] bf16
                           const short* __restrict__ F1wb,  // [64][128] bf16
                           const float* __restrict__ F1b,   // [64]
                           const short* __restrict__ F2wb,  // [16][64] bf16
                           const float* __restrict__ F2b,   // [16]
                           float* __restrict__ policy)      // [32768][16]
{
    __shared__ short hsm[4][16 * H_LD];
    const int tid  = threadIdx.x;
    const int wv   = tid >> 6;
    const int lane = tid & 63;
    const int quad = lane >> 4;
    const int l16  = lane & 15;
    const int rowbase = blockIdx.x * 64 + wv * 16;

    short8 a[4];
    const short* xrow = x2 + (size_t)(rowbase + l16) * 128;
#pragma unroll
    for (int k = 0; k < 4; k++) a[k] = *(const short8*)(xrow + k * 32 + quad * 8);
    f32x4 acc[4];
#pragma unroll
    for (int j = 0; j < 4; j++) acc[j] = *(const f32x4*)&F1b[j * 16 + quad * 4];
#pragma unroll
    for (int k = 0; k < 4; k++)
#pragma unroll
        for (int j = 0; j < 4; j++) {
            short8 b8 = *(const short8*)(F1wb + (size_t)(j * 16 + l16) * 128 + k * 32 + quad * 8);
            acc[j] = MFMA(b8, a[k], acc[j]);
        }
    short* hh = &hsm[wv][0];
#pragma unroll
    for (int j = 0; j < 4; j++) {
        uint2v o = { pkbf(lrelu(acc[j][0]), lrelu(acc[j][1])),
                     pkbf(lrelu(acc[j][2]), lrelu(acc[j][3])) };
        *(uint2v*)&hh[l16 * H_LD + j * 16 + quad * 4] = o;
    }
    __syncthreads();

    f32x4 lg = *(const f32x4*)&F2b[quad * 4];
#pragma unroll
    for (int k = 0; k < 2; k++) {
        short8 a2 = *(const short8*)(hh + l16 * H_LD + k * 32 + quad * 8);
        short8 b2 = *(const short8*)(F2wb + (size_t)l16 * 64 + k * 32 + quad * 8);
        lg = MFMA(b2, a2, lg);
    }
    float m = fmaxf(fmaxf(lg[0], lg[1]), fmaxf(lg[2], lg[3]));
    m = fmaxf(m, __shfl_xor(m, 16, 64));
    m = fmaxf(m, __shfl_xor(m, 32, 64));
    f32x4 e;
    float s = 0.f;
#pragma unroll
    for (int r = 0; r < 4; r++) { e[r] = __expf(lg[r] - m); s += e[r]; }
    s += __shfl_xor(s, 16, 64);
    s += __shfl_xor(s, 32, 64);
    float inv = 1.0f / s;
    f32x4 p4 = { e[0] * inv, e[1] * inv, e[2] * inv, e[3] * inv };
    __builtin_nontemporal_store(p4, (f32x4*)&policy[(size_t)(rowbase + l16) * 16 + quad * 4]);
}

// ---------------- launcher ----------------
extern "C" void kernel_launch(void* const* d_in, const int* in_sizes, int n_in,
                              void* d_out, int out_size, void* d_ws, size_t ws_size,
                              hipStream_t stream) {
    const float* states = (const float*)d_in[0];
    const float* E1w = (const float*)d_in[1];  const float* E1b = (const float*)d_in[2];
    const float* K1w = (const float*)d_in[3];  const float* K1b = (const float*)d_in[4];
    const float* Q1w = (const float*)d_in[5];  const float* Q1b = (const float*)d_in[6];
    const float* V1w = (const float*)d_in[7];  const float* V1b = (const float*)d_in[8];
    const float* E2w = (const float*)d_in[9];  const float* E2b = (const float*)d_in[10];
    const float* K2w = (const float*)d_in[11]; const float* K2b = (const float*)d_in[12];
    const float* Q2w = (const float*)d_in[13]; const float* Q2b = (const float*)d_in[14];
    const float* V2w = (const float*)d_in[15]; const float* V2b = (const float*)d_in[16];
    const float* F1w = (const float*)d_in[17]; const float* F1b = (const float*)d_in[18];
    const float* F2w = (const float*)d_in[19]; const float* F2b = (const float*)d_in[20];
    (void)K1b; (void)K2b;   // kb terms cancel in softmax; K bias enters only via wvec

    float* out    = (float*)d_out;
    float* policy = out;                        // [512][64][16]
    float* w1     = out + 512 * 64 * 16;        // [4][512][64][64]
    float* w2     = w1 + 4 * 512 * 64 * 64;     // [4][512][64][64]

    // ws layout (shorts): x1b | x2b | bf16 weights | gt | wvec
    short* wsb = (short*)d_ws;
    short* x1b = wsb;                           // [512][64][128] = 4,194,304 shorts
    short* x2b = wsb + 4194304;                 // [512][64][128]
    short* wts = wsb + 8388608;
    short* wE1 = wts;                // [4][128][256] = 131072
    short* wV1 = wts + 131072;       // [4][32][128]  = 16384
    short* wE2 = wts + 147456;       // [4][128][128] = 65536
    short* wV2 = wts + 212992;       // 16384
    short* wF1 = wts + 229376;       // 8192
    short* wF2 = wts + 237568;       // 1024
    short* gt  = wts + 238592;       // [8][128][128] = 131072 shorts
    float* wvec = (float*)(wts + 238592 + 131072);  // [8][128] fp32

    ConvArgs ca;
    ca.src[0] = E1w; ca.src[1] = V1w; ca.src[2] = E2w; ca.src[3] = V2w;
    ca.src[4] = F1w; ca.src[5] = F2w;
    ca.end[0] = 32768;  ca.end[1] = 36864;  ca.end[2] = 53248;  ca.end[3] = 57344;
    ca.end[4] = 59392;  ca.end[5] = 59648;
    convert_weights_kernel<<<233, 256, 0, stream>>>(ca, wts);
    precompute_gt_kernel<<<64, 256, 0, stream>>>(Q1w, K1w, Q1b, Q2w, K2w, Q2b, gt, wvec);

    attn_stage_kernel<256, true><<<2048, 256, 0, stream>>>(
        (const void*)states, wE1, E1b, gt, wvec, wV1, V1b, w1, x1b);
    attn_stage_kernel<128, false><<<2048, 256, 0, stream>>>(
        (const void*)x1b, wE2, E2b, gt + 65536, wvec + 512, wV2, V2b, w2, x2b);
    final_mlp_mfma_kernel<<<512, 256, 0, stream>>>(x2b, wF1, F1b, wF2, F2b, policy);
}

// Round 5
// 226.432 us; speedup vs baseline: 1.5529x; 1.5529x over previous
//
#include <hip/hip_runtime.h>

// ---------------- types / helpers ----------------
typedef __attribute__((ext_vector_type(8))) short short8;   // 8 bf16 = 4 VGPRs (MFMA A/B frag)
typedef __attribute__((ext_vector_type(4))) float f32x4;    // MFMA C/D frag
typedef __attribute__((ext_vector_type(2))) unsigned uint2v;

#define MFMA(a, b, c) __builtin_amdgcn_mfma_f32_16x16x32_bf16((a), (b), (c), 0, 0, 0)

__device__ __forceinline__ short f2bf(float f) {   // RNE float->bf16 (bit pattern as short)
    union { float f; unsigned u; } v; v.f = f;
    unsigned r = v.u + 0x7fffu + ((v.u >> 16) & 1u);
    return (short)(r >> 16);
}
__device__ __forceinline__ float bf2f(short s) {
    union { unsigned u; float f; } v; v.u = ((unsigned)(unsigned short)s) << 16; return v.f;
}
// pack two floats -> 2 bf16 in one u32 (pure integer ops; verified rounds 3/4)
__device__ __forceinline__ unsigned pkbf(float lo, float hi) {
    return (unsigned)(unsigned short)f2bf(lo) | ((unsigned)(unsigned short)f2bf(hi) << 16);
}
__device__ __forceinline__ float lrelu(float v) { return (v >= 0.f) ? v : 0.01f * v; }

// async global->LDS, 16B per lane; lds ptr must be wave-uniform (HW: base + lane*16)
__device__ __forceinline__ void load_lds16(const void* g, void* l) {
    __builtin_amdgcn_global_load_lds((const __attribute__((address_space(1))) void*)g,
                                     (__attribute__((address_space(3))) void*)l, 16, 0, 0);
}

// ---------------- fp32 -> bf16 conversion (weights + states), once per launch ----------------
// 7 segments: E1,V1,E2,V2,F1,F2 -> dstw contiguous; states -> dstx  (round-1-verified table)
struct ConvArgs { const float* src[7]; int end[7]; };  // end[] in float4 units, cumulative

__global__ __launch_bounds__(256) void convert_weights_kernel(ConvArgs a,
                                                              short* __restrict__ dstw,
                                                              short* __restrict__ dstx) {
    int i4 = blockIdx.x * 256 + threadIdx.x;           // exactly 2,156,800 float4s
    int seg = 0;
#pragma unroll
    for (int s = 0; s < 6; s++) seg += (i4 >= a.end[s]) ? 1 : 0;
    int base = (seg == 0) ? 0 : a.end[seg - 1];
    float4 v = ((const float4*)a.src[seg])[i4 - base];
    uint2v o = { pkbf(v.x, v.y), pkbf(v.z, v.w) };
    short* dst = (seg == 6) ? (dstx + (size_t)(i4 - a.end[5]) * 4)
                            : (dstw + (size_t)i4 * 4);
    *(uint2v*)dst = o;
}

// ---------------- precompute Gt = (Qw^T Kw)/sqrt(d) (bf16) and wvec = (qb^T Kw)/sqrt(d) ----------------
// Re-gridded: 512 blocks x 256 threads; block = (s,h,fg), thread = (f in {fg*2, fg*2+1}, e 0..127).
// Qw loads coalesced over e; Kw load scalar-broadcast per half-block.
__global__ __launch_bounds__(256) void precompute_gt_kernel(
    const float* __restrict__ Q1w, const float* __restrict__ K1w, const float* __restrict__ Q1b,
    const float* __restrict__ Q2w, const float* __restrict__ K2w, const float* __restrict__ Q2b,
    short* __restrict__ gt, float* __restrict__ wvec) {
    const int s  = blockIdx.x >> 8;
    const int h  = (blockIdx.x >> 6) & 3;
    const int fg = blockIdx.x & 63;
    const float* Qw = (s ? Q2w : Q1w) + (size_t)h * 16384;
    const float* Kw = (s ? K2w : K1w) + (size_t)h * 16384;
    const float* qb = (s ? Q2b : Q1b) + h * 128;
    const int f = fg * 2 + (threadIdx.x >> 7);
    const int e = threadIdx.x & 127;
    float acc = 0.f, accw = 0.f;
#pragma unroll 8
    for (int c = 0; c < 128; c++) {
        float kv = Kw[c * 128 + f];
        acc  = fmaf(Qw[c * 128 + e], kv, acc);
        accw = fmaf(qb[c], kv, accw);
    }
    const float scale = 0.08838834764831845f;     // 1/sqrt(128)
    gt[((size_t)((s * 4 + h) * 128 + f)) * 128 + e] = f2bf(acc * scale);
    if (e == 0) wvec[(s * 4 + h) * 128 + f] = accw * scale;
}

// ---------------- fused attention stage (round-3 structure + glds staging + swizzled X/T) ----------------
// LDS (short offsets):
//   X  [64][IN]  @0, PADLESS, XOR-swizzled: LDS[r][chunk c] holds X[r][c ^ (r&7)] (16B chunks).
//     After X dies (barrier 2): T/W [64][128] (same swizzle) overlays @0;
//     stage1 also hosts VT+CB in X tail (@8192).
//   SE [64][136] @64*IN  (round-3 layout, unswizzled)
//   stage2: VT [32][72] + CB float[64] after SE.
// stage1: 50,176 B -> 3 blocks/CU;  stage2: 38,656 B -> 4 blocks/CU.
template<int IN>
__global__ __launch_bounds__(256, (IN == 256) ? 3 : 4) void attn_stage_kernel(
    const short* __restrict__ xin,                      // [512][64][IN] bf16
    const short* __restrict__ Ew, const float* __restrict__ Eb,   // Ew bf16 [4][128][IN]
    const short* __restrict__ Gt, const float* __restrict__ wvec, // [4][128][128] bf16, [4][128] f32
    const short* __restrict__ Vw, const float* __restrict__ Vb,   // [4][32][128]
    float* __restrict__ w_out,                          // [4][512][64][64] fp32
    short* __restrict__ x_out)                          // [512][64][128] bf16
{
    constexpr int OFF_T  = 0;                                   // over X region
    constexpr int OFF_SE = 64 * IN;
    constexpr int OFF_VT = (IN == 256) ? 8192 : (64 * IN + 8704);
    constexpr int OFF_CB = OFF_VT + 2304;
    constexpr int SMEM   = (IN == 256) ? 25088 : 19328;
    __shared__ short sm[SMEM];

    const int tid  = threadIdx.x;
    // XCD-affinity decode: the 4 h-blocks of one b share blockIdx%8 -> same XCD L2.
    const int b    = blockIdx.x & 511;
    const int h    = blockIdx.x >> 9;
    const int wv   = tid >> 6;          // wave 0..3
    const int lane = tid & 63;
    const int quad = lane >> 4;
    const int l16  = lane & 15;
    const int myrow = wv * 16 + l16;
    constexpr int NK1 = IN / 32;

    // ---- stage X via global_load_lds (pre-swizzled source, linear LDS dest) ----
    {
        const short* xg = xin + (size_t)b * 64 * IN;
#pragma unroll
        for (int t = 0; t < IN / 32; t++) {
            int off   = wv * 16 * IN + t * 512 + lane * 8;   // short index this lane will receive
            int row   = off / IN;
            int chunk = (off % IN) >> 3;
            int src   = row * IN + ((chunk ^ (row & 7)) << 3);
            load_lds16(xg + src, &sm[wv * 16 * IN + t * 512]);
        }
    }

    // ---- prefetch phase-1 weight frags (A operand: Ew rows) while glds is in flight ----
    short8 ebf[NK1 * 2];
    {
        const short* ewh = Ew + (size_t)h * 128 * IN;
#pragma unroll
        for (int k0i = 0; k0i < NK1; k0i++)
#pragma unroll
            for (int j = 0; j < 2; j++)
                ebf[k0i * 2 + j] = *(const short8*)(ewh + (size_t)(wv * 32 + j * 16 + l16) * IN + k0i * 32 + quad * 8);
    }
    __syncthreads();   // B1: X staged (vmcnt drained by compiler)

    short8 gtf[8];   // G frags, prefetched during phase-1 epilogue

    // ---- Phase 1 (swapped): C[e][n] = Ew x X^T; col-split: wave -> cols wv*32..+31, all 64 rows ----
    {
        f32x4 acc[4][2];
#pragma unroll
        for (int j = 0; j < 2; j++) {
            f32x4 eb4 = *(const f32x4*)&Eb[h * 128 + wv * 32 + j * 16 + quad * 4];
#pragma unroll
            for (int i = 0; i < 4; i++) acc[i][j] = eb4;
        }
        __builtin_amdgcn_s_setprio(1);
#pragma unroll
        for (int k0i = 0; k0i < NK1; k0i++) {
            short8 x8[4];
#pragma unroll
            for (int i = 0; i < 4; i++) {
                int xrow = i * 16 + l16;
                int kc = k0i * 4 + quad;
                x8[i] = *(const short8*)&sm[xrow * IN + ((kc ^ (xrow & 7)) << 3)];
            }
#pragma unroll
            for (int i = 0; i < 4; i++)
#pragma unroll
                for (int j = 0; j < 2; j++)
                    acc[i][j] = MFMA(ebf[k0i * 2 + j], x8[i], acc[i][j]);
        }
        __builtin_amdgcn_s_setprio(0);
        // hoisted prefetch: G frags fly during epilogue + barrier (ebf now dead)
        {
            const short* gth = Gt + (size_t)h * 16384;
#pragma unroll
            for (int k0i = 0; k0i < 4; k0i++)
#pragma unroll
                for (int j = 0; j < 2; j++)
                    gtf[k0i * 2 + j] = *(const short8*)(gth + (size_t)(wv * 32 + j * 16 + l16) * 128 + k0i * 32 + quad * 8);
        }
        // SE[n][e]: n = i*16+l16, e = wv*32 + j*16 + quad*4 + r (contiguous) — round-3 layout
#pragma unroll
        for (int i = 0; i < 4; i++)
#pragma unroll
            for (int j = 0; j < 2; j++) {
                uint2v o = { pkbf(lrelu(acc[i][j][0]), lrelu(acc[i][j][1])),
                             pkbf(lrelu(acc[i][j][2]), lrelu(acc[i][j][3])) };
                *(uint2v*)&sm[OFF_SE + (i * 16 + l16) * 136 + wv * 32 + j * 16 + quad * 4] = o;
            }
    }
    __syncthreads();   // B2: SE published; X dead (T overlays)

    // ---- Phase 2: T = SE @ G^T (swapped, swizzled write into X region); V; cb ----
    {
        f32x4 tacc[4][2];
        f32x4 z = {0.f, 0.f, 0.f, 0.f};
#pragma unroll
        for (int i = 0; i < 4; i++)
#pragma unroll
            for (int j = 0; j < 2; j++) tacc[i][j] = z;
        __builtin_amdgcn_s_setprio(1);
#pragma unroll
        for (int k0i = 0; k0i < 4; k0i++) {
            short8 se8[4];
#pragma unroll
            for (int i = 0; i < 4; i++)
                se8[i] = *(const short8*)&sm[OFF_SE + (i * 16 + l16) * 136 + k0i * 32 + quad * 8];
#pragma unroll
            for (int i = 0; i < 4; i++)
#pragma unroll
                for (int j = 0; j < 2; j++)
                    tacc[i][j] = MFMA(gtf[k0i * 2 + j], se8[i], tacc[i][j]);
        }
        // T[n][f] swizzled: chunk c = (wv*32+j*16+quad*4)>>3, stored at c^(n&7)
#pragma unroll
        for (int i = 0; i < 4; i++)
#pragma unroll
            for (int j = 0; j < 2; j++) {
                uint2v ot = { pkbf(tacc[i][j][0], tacc[i][j][1]),
                              pkbf(tacc[i][j][2], tacc[i][j][3]) };
                int trow = i * 16 + l16;
                int c = wv * 4 + j * 2 + (quad >> 1);
                *(uint2v*)&sm[OFF_T + trow * 128 + ((c ^ (trow & 7)) << 3) + (quad & 1) * 4] = ot;
            }

        // v = leaky(SE @ Vw^T + Vb): round-3 pattern, VT[o][n]
        const short* vwh = Vw + (size_t)h * 32 * 128;
        const int n0v = (wv >> 1) * 16, mrow = (wv & 1) * 32;
        short8 vbf[4];
#pragma unroll
        for (int k0i = 0; k0i < 4; k0i++)
            vbf[k0i] = *(const short8*)(vwh + (size_t)(n0v + l16) * 128 + k0i * 32 + quad * 8);
        float vb = Vb[h * 32 + n0v + l16];
        f32x4 vacc[2];
        vacc[0] = (f32x4){vb, vb, vb, vb}; vacc[1] = vacc[0];
#pragma unroll
        for (int k0i = 0; k0i < 4; k0i++) {
            short8 a0 = *(const short8*)&sm[OFF_SE + (mrow + l16) * 136 + k0i * 32 + quad * 8];
            short8 a1 = *(const short8*)&sm[OFF_SE + (mrow + 16 + l16) * 136 + k0i * 32 + quad * 8];
            vacc[0] = MFMA(a0, vbf[k0i], vacc[0]);
            vacc[1] = MFMA(a1, vbf[k0i], vacc[1]);
        }
        __builtin_amdgcn_s_setprio(0);
#pragma unroll
        for (int i = 0; i < 2; i++) {
            uint2v ov = { pkbf(lrelu(vacc[i][0]), lrelu(vacc[i][1])),
                          pkbf(lrelu(vacc[i][2]), lrelu(vacc[i][3])) };
            *(uint2v*)&sm[OFF_VT + (n0v + l16) * 72 + mrow + i * 16 + quad * 4] = ov;
        }

        // cb[k] = SE_k . wvec  (logit column bias; row-constant terms cancel in softmax)
        {
            const float* wvh = wvec + h * 128;
            const int row = wv * 16 + (lane >> 2);
            const int e0 = (lane & 3) * 32;
            float s = 0.f;
#pragma unroll
            for (int u = 0; u < 32; u += 8) {
                short8 sv = *(const short8*)&sm[OFF_SE + row * 136 + e0 + u];
                float4 w0 = *(const float4*)(wvh + e0 + u);
                float4 w1 = *(const float4*)(wvh + e0 + u + 4);
                s = fmaf(bf2f(sv[0]), w0.x, s); s = fmaf(bf2f(sv[1]), w0.y, s);
                s = fmaf(bf2f(sv[2]), w0.z, s); s = fmaf(bf2f(sv[3]), w0.w, s);
                s = fmaf(bf2f(sv[4]), w1.x, s); s = fmaf(bf2f(sv[5]), w1.y, s);
                s = fmaf(bf2f(sv[6]), w1.z, s); s = fmaf(bf2f(sv[7]), w1.w, s);
            }
            s += __shfl_xor(s, 1, 4);
            s += __shfl_xor(s, 2, 4);
            if ((lane & 3) == 0) ((float*)&sm[OFF_CB])[row] = s;
        }
    }
    __syncthreads();   // B3: T, VT, CB published

    // ---- Phase 3 (swapped): C[k][q=myrow]; T frags via swizzled reads ----
    f32x4 lacc[4];
#pragma unroll
    for (int jj = 0; jj < 4; jj++) lacc[jj] = (f32x4){0.f, 0.f, 0.f, 0.f};
    __builtin_amdgcn_s_setprio(1);
#pragma unroll
    for (int k0 = 0; k0 < 128; k0 += 32) {
        int kc = (k0 >> 3) + quad;
        short8 tf = *(const short8*)&sm[OFF_T + myrow * 128 + ((kc ^ (myrow & 7)) << 3)];
#pragma unroll
        for (int jj = 0; jj < 4; jj++) {
            short8 af = *(const short8*)&sm[OFF_SE + (jj * 16 + l16) * 136 + k0 + quad * 8];
            lacc[jj] = MFMA(af, tf, lacc[jj]);
        }
    }
    __builtin_amdgcn_s_setprio(0);

    // ---- softmax (per-lane row): W overlays own T row (swizzled); full-line NT w_out ----
    {
        const float* cbf = (const float*)&sm[OFF_CB];
#pragma unroll
        for (int jj = 0; jj < 4; jj++) {
            f32x4 cb4 = *(const f32x4*)&cbf[jj * 16 + quad * 4];
            lacc[jj] += cb4;
        }
        float m01 = fmaxf(fmaxf(lacc[0][0], lacc[0][1]), fmaxf(lacc[0][2], lacc[0][3]));
        float m23 = fmaxf(fmaxf(lacc[1][0], lacc[1][1]), fmaxf(lacc[1][2], lacc[1][3]));
        float m45 = fmaxf(fmaxf(lacc[2][0], lacc[2][1]), fmaxf(lacc[2][2], lacc[2][3]));
        float m67 = fmaxf(fmaxf(lacc[3][0], lacc[3][1]), fmaxf(lacc[3][2], lacc[3][3]));
        float m = fmaxf(fmaxf(m01, m23), fmaxf(m45, m67));
        m = fmaxf(m, __shfl_xor(m, 16, 64));
        m = fmaxf(m, __shfl_xor(m, 32, 64));
        float sum = 0.f;
#pragma unroll
        for (int jj = 0; jj < 4; jj++)
#pragma unroll
            for (int r = 0; r < 4; r++) {
                float e = __expf(lacc[jj][r] - m);   // scale pre-folded into Gt/wvec
                lacc[jj][r] = e; sum += e;
            }
        sum += __shfl_xor(sum, 16, 64);
        sum += __shfl_xor(sum, 32, 64);
        float inv = 1.0f / sum;
        float* wbase = w_out + ((size_t)(h * 512 + b)) * 4096 + (size_t)myrow * 64;
#pragma unroll
        for (int jj = 0; jj < 4; jj++) {
            f32x4 w4 = { lacc[jj][0] * inv, lacc[jj][1] * inv, lacc[jj][2] * inv, lacc[jj][3] * inv };
            uint2v o = { pkbf(w4[0], w4[1]), pkbf(w4[2], w4[3]) };
            int c = jj * 2 + (quad >> 1);
            *(uint2v*)&sm[OFF_T + myrow * 128 + ((c ^ (myrow & 7)) << 3) + (quad & 1) * 4] = o;
            __builtin_nontemporal_store(w4, (f32x4*)(wbase + jj * 16 + quad * 4));  // full 64B lines
        }
    }
    // no barrier: P4 reads VT/CB (published B3) + own W rows (same-wave ds ordering)

    // ---- Phase 4 (swapped): att C[o][q=myrow]; packed 8B x_out stores ----
    {
        f32x4 aacc[2]; aacc[0] = (f32x4){0.f, 0.f, 0.f, 0.f}; aacc[1] = aacc[0];
#pragma unroll
        for (int k0 = 0; k0 < 64; k0 += 32) {
            int kc = (k0 >> 3) + quad;
            short8 wf = *(const short8*)&sm[OFF_T + myrow * 128 + ((kc ^ (myrow & 7)) << 3)];
#pragma unroll
            for (int o = 0; o < 2; o++) {
                short8 vf = *(const short8*)&sm[OFF_VT + (o * 16 + l16) * 72 + k0 + quad * 8];
                aacc[o] = MFMA(vf, wf, aacc[o]);
            }
        }
        short* xob = x_out + (size_t)b * 8192 + (size_t)myrow * 128 + h * 32;
#pragma unroll
        for (int o = 0; o < 2; o++) {
            uint2v o8 = { pkbf(aacc[o][0], aacc[o][1]), pkbf(aacc[o][2], aacc[o][3]) };
            *(uint2v*)&xob[o * 16 + quad * 4] = o8;
        }
    }
}

// ---------------- final MLP + softmax (round-3 verified, unchanged) ----------------
#define H_LD 72
__global__ __launch_bounds__(256)
void final_mlp_mfma_kernel(const short* __restrict__ x2,    // [32768][128] bf16
                           const short* __restrict__ F1wb,  // [64][128] bf16
                           const float* __restrict__ F1b,   // [64]
                           const short* __restrict__ F2wb,  // [16][64] bf16
                           const float* __restrict__ F2b,   // [16]
                           float* __restrict__ policy)      // [32768][16]
{
    __shared__ short hsm[4][16 * H_LD];
    const int tid  = threadIdx.x;
    const int wv   = tid >> 6;
    const int lane = tid & 63;
    const int quad = lane >> 4;
    const int l16  = lane & 15;
    const int rowbase = blockIdx.x * 64 + wv * 16;

    short8 a[4];
    const short* xrow = x2 + (size_t)(rowbase + l16) * 128;
#pragma unroll
    for (int k = 0; k < 4; k++) a[k] = *(const short8*)(xrow + k * 32 + quad * 8);
    f32x4 acc[4];
#pragma unroll
    for (int j = 0; j < 4; j++) acc[j] = *(const f32x4*)&F1b[j * 16 + quad * 4];
#pragma unroll
    for (int k = 0; k < 4; k++)
#pragma unroll
        for (int j = 0; j < 4; j++) {
            short8 b8 = *(const short8*)(F1wb + (size_t)(j * 16 + l16) * 128 + k * 32 + quad * 8);
            acc[j] = MFMA(b8, a[k], acc[j]);
        }
    short* hh = &hsm[wv][0];
#pragma unroll
    for (int j = 0; j < 4; j++) {
        uint2v o = { pkbf(lrelu(acc[j][0]), lrelu(acc[j][1])),
                     pkbf(lrelu(acc[j][2]), lrelu(acc[j][3])) };
        *(uint2v*)&hh[l16 * H_LD + j * 16 + quad * 4] = o;
    }
    __syncthreads();

    f32x4 lg = *(const f32x4*)&F2b[quad * 4];
#pragma unroll
    for (int k = 0; k < 2; k++) {
        short8 a2 = *(const short8*)(hh + l16 * H_LD + k * 32 + quad * 8);
        short8 b2 = *(const short8*)(F2wb + (size_t)l16 * 64 + k * 32 + quad * 8);
        lg = MFMA(b2, a2, lg);
    }
    float m = fmaxf(fmaxf(lg[0], lg[1]), fmaxf(lg[2], lg[3]));
    m = fmaxf(m, __shfl_xor(m, 16, 64));
    m = fmaxf(m, __shfl_xor(m, 32, 64));
    f32x4 e;
    float s = 0.f;
#pragma unroll
    for (int r = 0; r < 4; r++) { e[r] = __expf(lg[r] - m); s += e[r]; }
    s += __shfl_xor(s, 16, 64);
    s += __shfl_xor(s, 32, 64);
    float inv = 1.0f / s;
    f32x4 p4 = { e[0] * inv, e[1] * inv, e[2] * inv, e[3] * inv };
    __builtin_nontemporal_store(p4, (f32x4*)&policy[(size_t)(rowbase + l16) * 16 + quad * 4]);
}

// ---------------- launcher ----------------
extern "C" void kernel_launch(void* const* d_in, const int* in_sizes, int n_in,
                              void* d_out, int out_size, void* d_ws, size_t ws_size,
                              hipStream_t stream) {
    const float* states = (const float*)d_in[0];
    const float* E1w = (const float*)d_in[1];  const float* E1b = (const float*)d_in[2];
    const float* K1w = (const float*)d_in[3];  const float* K1b = (const float*)d_in[4];
    const float* Q1w = (const float*)d_in[5];  const float* Q1b = (const float*)d_in[6];
    const float* V1w = (const float*)d_in[7];  const float* V1b = (const float*)d_in[8];
    const float* E2w = (const float*)d_in[9];  const float* E2b = (const float*)d_in[10];
    const float* K2w = (const float*)d_in[11]; const float* K2b = (const float*)d_in[12];
    const float* Q2w = (const float*)d_in[13]; const float* Q2b = (const float*)d_in[14];
    const float* V2w = (const float*)d_in[15]; const float* V2b = (const float*)d_in[16];
    const float* F1w = (const float*)d_in[17]; const float* F1b = (const float*)d_in[18];
    const float* F2w = (const float*)d_in[19]; const float* F2b = (const float*)d_in[20];
    (void)K1b; (void)K2b;   // kb terms cancel in softmax; K bias enters only via wvec

    float* out    = (float*)d_out;
    float* policy = out;                        // [512][64][16]
    float* w1     = out + 512 * 64 * 16;        // [4][512][64][64]
    float* w2     = w1 + 4 * 512 * 64 * 64;     // [4][512][64][64]

    // ws layout (shorts): x1b | xsb (states bf16; x2b aliases it after stage1) | wts | gt | wvec
    short* wsb = (short*)d_ws;
    short* x1b = wsb;                           // [512][64][128] = 4,194,304 shorts
    short* xsb = wsb + 4194304;                 // [512][64][256] = 8,388,608 shorts
    short* x2b = xsb;                           // alias: xsb dead once stage1 done
    short* wts = wsb + 12582912;
    short* wE1 = wts;                // [4][128][256] = 131072
    short* wV1 = wts + 131072;       // [4][32][128]  = 16384
    short* wE2 = wts + 147456;       // [4][128][128] = 65536
    short* wV2 = wts + 212992;       // 16384
    short* wF1 = wts + 229376;       // 8192
    short* wF2 = wts + 237568;       // 1024
    short* gt  = wts + 238592;       // [8][128][128] = 131072 shorts
    float* wvec = (float*)(wts + 238592 + 131072);  // [8][128] fp32

    ConvArgs ca;
    ca.src[0] = E1w; ca.src[1] = V1w; ca.src[2] = E2w; ca.src[3] = V2w;
    ca.src[4] = F1w; ca.src[5] = F2w; ca.src[6] = states;
    ca.end[0] = 32768;  ca.end[1] = 36864;  ca.end[2] = 53248;  ca.end[3] = 57344;
    ca.end[4] = 59392;  ca.end[5] = 59648;  ca.end[6] = 2156800;
    convert_weights_kernel<<<8425, 256, 0, stream>>>(ca, wts, xsb);
    precompute_gt_kernel<<<512, 256, 0, stream>>>(Q1w, K1w, Q1b, Q2w, K2w, Q2b, gt, wvec);

    attn_stage_kernel<256><<<2048, 256, 0, stream>>>(
        xsb, wE1, E1b, gt, wvec, wV1, V1b, w1, x1b);
    attn_stage_kernel<128><<<2048, 256, 0, stream>>>(
        x1b, wE2, E2b, gt + 65536, wvec + 512, wV2, V2b, w2, x2b);
    final_mlp_mfma_kernel<<<512, 256, 0, stream>>>(x2b, wF1, F1b, wF2, F2b, policy);
}

// Round 6
// 217.851 us; speedup vs baseline: 1.6140x; 1.0394x over previous
//
#include <hip/hip_runtime.h>

// ---------------- types / helpers ----------------
typedef __attribute__((ext_vector_type(8))) short short8;   // 8 bf16 = 4 VGPRs (MFMA A/B frag)
typedef __attribute__((ext_vector_type(4))) float f32x4;    // MFMA C/D frag
typedef __attribute__((ext_vector_type(2))) unsigned uint2v;

#define MFMA(a, b, c) __builtin_amdgcn_mfma_f32_16x16x32_bf16((a), (b), (c), 0, 0, 0)

__device__ __forceinline__ short f2bf(float f) {   // RNE float->bf16 (bit pattern as short)
    union { float f; unsigned u; } v; v.f = f;
    unsigned r = v.u + 0x7fffu + ((v.u >> 16) & 1u);
    return (short)(r >> 16);
}
__device__ __forceinline__ float bf2f(short s) {
    union { unsigned u; float f; } v; v.u = ((unsigned)(unsigned short)s) << 16; return v.f;
}
// pack two floats -> 2 bf16 in one u32 (pure integer ops; verified rounds 3/4/5)
__device__ __forceinline__ unsigned pkbf(float lo, float hi) {
    return (unsigned)(unsigned short)f2bf(lo) | ((unsigned)(unsigned short)f2bf(hi) << 16);
}
__device__ __forceinline__ float lrelu(float v) { return (v >= 0.f) ? v : 0.01f * v; }

// async global->LDS, 16B per lane; lds ptr wave-uniform (HW: base + lane*16)
__device__ __forceinline__ void load_lds16(const void* g, void* l) {
    __builtin_amdgcn_global_load_lds((const __attribute__((address_space(1))) void*)g,
                                     (__attribute__((address_space(3))) void*)l, 16, 0, 0);
}

// ---------------- merged: fp32->bf16 conversion (weights+states) + Gt/wvec precompute ----------------
// blocks [0, 8425): convert; blocks [8425, 8937): precompute Gt = (Qw^T Kw)/sqrt(d), wvec = (qb^T Kw)/sqrt(d)
struct ConvArgs { const float* src[7]; int end[7]; };  // end[] in float4 units, cumulative (r5-verified)

__global__ __launch_bounds__(256) void conv_and_gt_kernel(ConvArgs a,
                                                          short* __restrict__ dstw,
                                                          short* __restrict__ dstx,
                                                          const float* __restrict__ Q1w, const float* __restrict__ K1w,
                                                          const float* __restrict__ Q1b,
                                                          const float* __restrict__ Q2w, const float* __restrict__ K2w,
                                                          const float* __restrict__ Q2b,
                                                          short* __restrict__ gt, float* __restrict__ wvec) {
    if (blockIdx.x < 8425) {
        int i4 = blockIdx.x * 256 + threadIdx.x;           // exactly 2,156,800 float4s
        int seg = 0;
#pragma unroll
        for (int s = 0; s < 6; s++) seg += (i4 >= a.end[s]) ? 1 : 0;
        int base = (seg == 0) ? 0 : a.end[seg - 1];
        float4 v = ((const float4*)a.src[seg])[i4 - base];
        uint2v o = { pkbf(v.x, v.y), pkbf(v.z, v.w) };
        short* dst = (seg == 6) ? (dstx + (size_t)(i4 - a.end[5]) * 4)
                                : (dstw + (size_t)i4 * 4);
        *(uint2v*)dst = o;
    } else {
        int bid = blockIdx.x - 8425;                       // 0..511
        const int s  = bid >> 8;
        const int h  = (bid >> 6) & 3;
        const int fg = bid & 63;
        const float* Qw = (s ? Q2w : Q1w) + (size_t)h * 16384;
        const float* Kw = (s ? K2w : K1w) + (size_t)h * 16384;
        const float* qb = (s ? Q2b : Q1b) + h * 128;
        const int f = fg * 2 + (threadIdx.x >> 7);
        const int e = threadIdx.x & 127;
        float acc = 0.f, accw = 0.f;
#pragma unroll 8
        for (int c = 0; c < 128; c++) {
            float kv = Kw[c * 128 + f];
            acc  = fmaf(Qw[c * 128 + e], kv, acc);
            accw = fmaf(qb[c], kv, accw);
        }
        const float scale = 0.08838834764831845f;          // 1/sqrt(128)
        gt[((size_t)((s * 4 + h) * 128 + f)) * 128 + e] = f2bf(acc * scale);
        if (e == 0) wvec[(s * 4 + h) * 128 + f] = accw * scale;
    }
}

// ---------------- fused attention stage: 2 heads/block, 8 waves, 2 blocks/CU ----------------
// Waves 0-3 -> head h0, waves 4-7 -> head h0+1 (col-split within head, round-5-verified patterns).
// LDS (short offsets), total 38,400 shorts = 76,800 B -> 2 blocks/CU:
//   X  [64][IN] @0, padless, XOR-swizzled (16B chunks: LDS[r][c] = X[r][c^(r&7)]); dead after P1.
//   T  per-head [64][128] @ hsel*8192 (overlays X region; W overlays own T rows after logits)
//   SE per-head [64][136] @ 16384 + hsel*8704
//   VT per-head [32][72]  @ 33792 + hsel*2304
// wvec folded into T init => no CB pass (logits+cb == SE . (T + wvec)).
template<int IN>
__global__ __launch_bounds__(512, 4) void attn_stage_kernel(
    const short* __restrict__ xin,                      // [512][64][IN] bf16
    const short* __restrict__ Ew, const float* __restrict__ Eb,   // Ew bf16 [4][128][IN]
    const short* __restrict__ Gt, const float* __restrict__ wvec, // [4][128][128] bf16, [4][128] f32
    const short* __restrict__ Vw, const float* __restrict__ Vb,   // [4][32][128]
    float* __restrict__ w_out,                          // [4][512][64][64] fp32
    short* __restrict__ x_out)                          // [512][64][128] bf16
{
    __shared__ short sm[38400];

    const int tid  = threadIdx.x;
    // XCD-affinity: blocks b and b+512 (the two head-pairs of one b) share blockIdx%8 -> same XCD L2.
    const int b    = blockIdx.x & 511;
    const int h0   = (blockIdx.x >> 9) << 1;
    const int wv8  = tid >> 6;          // wave 0..7
    const int hsel = wv8 >> 2;
    const int wvl  = wv8 & 3;           // wave-in-head 0..3
    const int h    = h0 + hsel;
    const int lane = tid & 63;
    const int quad = lane >> 4;
    const int l16  = lane & 15;
    const int myrow = wvl * 16 + l16;
    const int OFF_T  = hsel * 8192;
    const int OFF_SE = 16384 + hsel * 8704;
    const int OFF_VT = 33792 + hsel * 2304;
    constexpr int NK1 = IN / 32;

    // ---- stage X via global_load_lds (pre-swizzled source, linear LDS dest); 8 rows/wave ----
    {
        const short* xg = xin + (size_t)b * 64 * IN;
#pragma unroll
        for (int t = 0; t < IN / 64; t++) {
            int base  = wv8 * 8 * IN + t * 512;
            int off   = base + lane * 8;           // short index this lane receives
            int row   = off / IN;
            int chunk = (off % IN) >> 3;
            int src   = row * IN + ((chunk ^ (row & 7)) << 3);
            load_lds16(xg + src, &sm[base]);
        }
    }

    // ---- prefetch phase-1 weight frags (A operand: Ew rows of head h) while glds in flight ----
    short8 ebf[NK1 * 2];
    {
        const short* ewh = Ew + (size_t)h * 128 * IN;
#pragma unroll
        for (int k0i = 0; k0i < NK1; k0i++)
#pragma unroll
            for (int j = 0; j < 2; j++)
                ebf[k0i * 2 + j] = *(const short8*)(ewh + (size_t)(wvl * 32 + j * 16 + l16) * IN + k0i * 32 + quad * 8);
    }
    __syncthreads();   // B1: X staged

    short8 gtf[8];   // G frags, prefetched during phase-1 epilogue

    // ---- Phase 1 (swapped): C[e][n] = Ew x X^T; wave -> cols wvl*32..+31 of head h, all 64 rows ----
    {
        f32x4 acc[4][2];
#pragma unroll
        for (int j = 0; j < 2; j++) {
            f32x4 eb4 = *(const f32x4*)&Eb[h * 128 + wvl * 32 + j * 16 + quad * 4];
#pragma unroll
            for (int i = 0; i < 4; i++) acc[i][j] = eb4;
        }
        __builtin_amdgcn_s_setprio(1);
#pragma unroll
        for (int k0i = 0; k0i < NK1; k0i++) {
            short8 x8[4];
#pragma unroll
            for (int i = 0; i < 4; i++) {
                int xrow = i * 16 + l16;
                int kc = k0i * 4 + quad;
                x8[i] = *(const short8*)&sm[xrow * IN + ((kc ^ (xrow & 7)) << 3)];
            }
#pragma unroll
            for (int i = 0; i < 4; i++)
#pragma unroll
                for (int j = 0; j < 2; j++)
                    acc[i][j] = MFMA(ebf[k0i * 2 + j], x8[i], acc[i][j]);
        }
        __builtin_amdgcn_s_setprio(0);
        // hoisted prefetch: G frags fly during epilogue + barrier (ebf dead)
        {
            const short* gth = Gt + (size_t)h * 16384;
#pragma unroll
            for (int k0i = 0; k0i < 4; k0i++)
#pragma unroll
                for (int j = 0; j < 2; j++)
                    gtf[k0i * 2 + j] = *(const short8*)(gth + (size_t)(wvl * 32 + j * 16 + l16) * 128 + k0i * 32 + quad * 8);
        }
        // SE[n][e]: n = i*16+l16, e = wvl*32 + j*16 + quad*4 + r (contiguous)
#pragma unroll
        for (int i = 0; i < 4; i++)
#pragma unroll
            for (int j = 0; j < 2; j++) {
                uint2v o = { pkbf(lrelu(acc[i][j][0]), lrelu(acc[i][j][1])),
                             pkbf(lrelu(acc[i][j][2]), lrelu(acc[i][j][3])) };
                *(uint2v*)&sm[OFF_SE + (i * 16 + l16) * 136 + wvl * 32 + j * 16 + quad * 4] = o;
            }
    }
    __syncthreads();   // B2: SE (both heads) published; X dead (T overlays)

    // ---- Phase 2: T = SE @ G^T + wvec (bias-init!); V. cb pass eliminated by wvec fold ----
    {
        f32x4 tacc[4][2];
#pragma unroll
        for (int j = 0; j < 2; j++) {
            f32x4 wv4 = *(const f32x4*)&wvec[h * 128 + wvl * 32 + j * 16 + quad * 4];
#pragma unroll
            for (int i = 0; i < 4; i++) tacc[i][j] = wv4;
        }
        __builtin_amdgcn_s_setprio(1);
#pragma unroll
        for (int k0i = 0; k0i < 4; k0i++) {
            short8 se8[4];
#pragma unroll
            for (int i = 0; i < 4; i++)
                se8[i] = *(const short8*)&sm[OFF_SE + (i * 16 + l16) * 136 + k0i * 32 + quad * 8];
#pragma unroll
            for (int i = 0; i < 4; i++)
#pragma unroll
                for (int j = 0; j < 2; j++)
                    tacc[i][j] = MFMA(gtf[k0i * 2 + j], se8[i], tacc[i][j]);
        }
        // T[n][f] swizzled into head's T region: chunk c = (wvl*32+j*16+quad*4)>>3
#pragma unroll
        for (int i = 0; i < 4; i++)
#pragma unroll
            for (int j = 0; j < 2; j++) {
                uint2v ot = { pkbf(tacc[i][j][0], tacc[i][j][1]),
                              pkbf(tacc[i][j][2], tacc[i][j][3]) };
                int trow = i * 16 + l16;
                int c = wvl * 4 + j * 2 + (quad >> 1);
                *(uint2v*)&sm[OFF_T + trow * 128 + ((c ^ (trow & 7)) << 3) + (quad & 1) * 4] = ot;
            }

        // v = leaky(SE @ Vw^T + Vb): VT[o][n] (round-3/5 pattern, within head)
        const short* vwh = Vw + (size_t)h * 32 * 128;
        const int n0v = (wvl >> 1) * 16, mrow = (wvl & 1) * 32;
        short8 vbf[4];
#pragma unroll
        for (int k0i = 0; k0i < 4; k0i++)
            vbf[k0i] = *(const short8*)(vwh + (size_t)(n0v + l16) * 128 + k0i * 32 + quad * 8);
        float vb = Vb[h * 32 + n0v + l16];
        f32x4 vacc[2];
        vacc[0] = (f32x4){vb, vb, vb, vb}; vacc[1] = vacc[0];
#pragma unroll
        for (int k0i = 0; k0i < 4; k0i++) {
            short8 a0 = *(const short8*)&sm[OFF_SE + (mrow + l16) * 136 + k0i * 32 + quad * 8];
            short8 a1 = *(const short8*)&sm[OFF_SE + (mrow + 16 + l16) * 136 + k0i * 32 + quad * 8];
            vacc[0] = MFMA(a0, vbf[k0i], vacc[0]);
            vacc[1] = MFMA(a1, vbf[k0i], vacc[1]);
        }
        __builtin_amdgcn_s_setprio(0);
#pragma unroll
        for (int i = 0; i < 2; i++) {
            uint2v ov = { pkbf(lrelu(vacc[i][0]), lrelu(vacc[i][1])),
                          pkbf(lrelu(vacc[i][2]), lrelu(vacc[i][3])) };
            *(uint2v*)&sm[OFF_VT + (n0v + l16) * 72 + mrow + i * 16 + quad * 4] = ov;
        }
    }
    __syncthreads();   // B3: T, VT published

    // ---- Phase 3 (swapped): C[k][q=myrow]; T frags via swizzled reads ----
    f32x4 lacc[4];
#pragma unroll
    for (int jj = 0; jj < 4; jj++) lacc[jj] = (f32x4){0.f, 0.f, 0.f, 0.f};
    __builtin_amdgcn_s_setprio(1);
#pragma unroll
    for (int k0 = 0; k0 < 128; k0 += 32) {
        int kc = (k0 >> 3) + quad;
        short8 tf = *(const short8*)&sm[OFF_T + myrow * 128 + ((kc ^ (myrow & 7)) << 3)];
#pragma unroll
        for (int jj = 0; jj < 4; jj++) {
            short8 af = *(const short8*)&sm[OFF_SE + (jj * 16 + l16) * 136 + k0 + quad * 8];
            lacc[jj] = MFMA(af, tf, lacc[jj]);
        }
    }
    __builtin_amdgcn_s_setprio(0);

    // ---- softmax (per-lane row; cb already in logits via wvec fold); W overlays own T row ----
    {
        float m01 = fmaxf(fmaxf(lacc[0][0], lacc[0][1]), fmaxf(lacc[0][2], lacc[0][3]));
        float m23 = fmaxf(fmaxf(lacc[1][0], lacc[1][1]), fmaxf(lacc[1][2], lacc[1][3]));
        float m45 = fmaxf(fmaxf(lacc[2][0], lacc[2][1]), fmaxf(lacc[2][2], lacc[2][3]));
        float m67 = fmaxf(fmaxf(lacc[3][0], lacc[3][1]), fmaxf(lacc[3][2], lacc[3][3]));
        float m = fmaxf(fmaxf(m01, m23), fmaxf(m45, m67));
        m = fmaxf(m, __shfl_xor(m, 16, 64));
        m = fmaxf(m, __shfl_xor(m, 32, 64));
        float sum = 0.f;
#pragma unroll
        for (int jj = 0; jj < 4; jj++)
#pragma unroll
            for (int r = 0; r < 4; r++) {
                float e = __expf(lacc[jj][r] - m);   // scale pre-folded into Gt/wvec
                lacc[jj][r] = e; sum += e;
            }
        sum += __shfl_xor(sum, 16, 64);
        sum += __shfl_xor(sum, 32, 64);
        float inv = 1.0f / sum;
        float* wbase = w_out + ((size_t)(h * 512 + b)) * 4096 + (size_t)myrow * 64;
#pragma unroll
        for (int jj = 0; jj < 4; jj++) {
            f32x4 w4 = { lacc[jj][0] * inv, lacc[jj][1] * inv, lacc[jj][2] * inv, lacc[jj][3] * inv };
            uint2v o = { pkbf(w4[0], w4[1]), pkbf(w4[2], w4[3]) };
            int c = jj * 2 + (quad >> 1);
            *(uint2v*)&sm[OFF_T + myrow * 128 + ((c ^ (myrow & 7)) << 3) + (quad & 1) * 4] = o;
            __builtin_nontemporal_store(w4, (f32x4*)(wbase + jj * 16 + quad * 4));  // full 64B lines
        }
    }
    // no barrier: P4 reads VT (published B3) + own W row (same-wave ds ordering; rows wave-private post-B3)

    // ---- Phase 4 (swapped): att C[o][q=myrow]; packed 8B x_out stores ----
    {
        f32x4 aacc[2]; aacc[0] = (f32x4){0.f, 0.f, 0.f, 0.f}; aacc[1] = aacc[0];
#pragma unroll
        for (int k0 = 0; k0 < 64; k0 += 32) {
            int kc = (k0 >> 3) + quad;
            short8 wf = *(const short8*)&sm[OFF_T + myrow * 128 + ((kc ^ (myrow & 7)) << 3)];
#pragma unroll
            for (int o = 0; o < 2; o++) {
                short8 vf = *(const short8*)&sm[OFF_VT + (o * 16 + l16) * 72 + k0 + quad * 8];
                aacc[o] = MFMA(vf, wf, aacc[o]);
            }
        }
        short* xob = x_out + (size_t)b * 8192 + (size_t)myrow * 128 + h * 32;
#pragma unroll
        for (int o = 0; o < 2; o++) {
            uint2v o8 = { pkbf(aacc[o][0], aacc[o][1]), pkbf(aacc[o][2], aacc[o][3]) };
            *(uint2v*)&xob[o * 16 + quad * 4] = o8;
        }
    }
}

// ---------------- final MLP + softmax (round-3/5 verified, unchanged) ----------------
#define H_LD 72
__global__ __launch_bounds__(256)
void final_mlp_mfma_kernel(const short* __restrict__ x2,    // [32768][128] bf16
                           const short* __restrict__ F1wb,  // [64][128] bf16
                           const float* __restrict__ F1b,   // [64]
                           const short* __restrict__ F2wb,  // [16][64] bf16
                           const float* __restrict__ F2b,   // [16]
                           float* __restrict__ policy)      // [32768][16]
{
    __shared__ short hsm[4][16 * H_LD];
    const int tid  = threadIdx.x;
    const int wv   = tid >> 6;
    const int lane = tid & 63;
    const int quad = lane >> 4;
    const int l16  = lane & 15;
    const int rowbase = blockIdx.x * 64 + wv * 16;

    short8 a[4];
    const short* xrow = x2 + (size_t)(rowbase + l16) * 128;
#pragma unroll
    for (int k = 0; k < 4; k++) a[k] = *(const short8*)(xrow + k * 32 + quad * 8);
    f32x4 acc[4];
#pragma unroll
    for (int j = 0; j < 4; j++) acc[j] = *(const f32x4*)&F1b[j * 16 + quad * 4];
#pragma unroll
    for (int k = 0; k < 4; k++)
#pragma unroll
        for (int j = 0; j < 4; j++) {
            short8 b8 = *(const short8*)(F1wb + (size_t)(j * 16 + l16) * 128 + k * 32 + quad * 8);
            acc[j] = MFMA(b8, a[k], acc[j]);
        }
    short* hh = &hsm[wv][0];
#pragma unroll
    for (int j = 0; j < 4; j++) {
        uint2v o = { pkbf(lrelu(acc[j][0]), lrelu(acc[j][1])),
                     pkbf(lrelu(acc[j][2]), lrelu(acc[j][3])) };
        *(uint2v*)&hh[l16 * H_LD + j * 16 + quad * 4] = o;
    }
    __syncthreads();

    f32x4 lg = *(const f32x4*)&F2b[quad * 4];
#pragma unroll
    for (int k = 0; k < 2; k++) {
        short8 a2 = *(const short8*)(hh + l16 * H_LD + k * 32 + quad * 8);
        short8 b2 = *(const short8*)(F2wb + (size_t)l16 * 64 + k * 32 + quad * 8);
        lg = MFMA(b2, a2, lg);
    }
    float m = fmaxf(fmaxf(lg[0], lg[1]), fmaxf(lg[2], lg[3]));
    m = fmaxf(m, __shfl_xor(m, 16, 64));
    m = fmaxf(m, __shfl_xor(m, 32, 64));
    f32x4 e;
    float s = 0.f;
#pragma unroll
    for (int r = 0; r < 4; r++) { e[r] = __expf(lg[r] - m); s += e[r]; }
    s += __shfl_xor(s, 16, 64);
    s += __shfl_xor(s, 32, 64);
    float inv = 1.0f / s;
    f32x4 p4 = { e[0] * inv, e[1] * inv, e[2] * inv, e[3] * inv };
    __builtin_nontemporal_store(p4, (f32x4*)&policy[(size_t)(rowbase + l16) * 16 + quad * 4]);
}

// ---------------- launcher ----------------
extern "C" void kernel_launch(void* const* d_in, const int* in_sizes, int n_in,
                              void* d_out, int out_size, void* d_ws, size_t ws_size,
                              hipStream_t stream) {
    const float* states = (const float*)d_in[0];
    const float* E1w = (const float*)d_in[1];  const float* E1b = (const float*)d_in[2];
    const float* K1w = (const float*)d_in[3];  const float* K1b = (const float*)d_in[4];
    const float* Q1w = (const float*)d_in[5];  const float* Q1b = (const float*)d_in[6];
    const float* V1w = (const float*)d_in[7];  const float* V1b = (const float*)d_in[8];
    const float* E2w = (const float*)d_in[9];  const float* E2b = (const float*)d_in[10];
    const float* K2w = (const float*)d_in[11]; const float* K2b = (const float*)d_in[12];
    const float* Q2w = (const float*)d_in[13]; const float* Q2b = (const float*)d_in[14];
    const float* V2w = (const float*)d_in[15]; const float* V2b = (const float*)d_in[16];
    const float* F1w = (const float*)d_in[17]; const float* F1b = (const float*)d_in[18];
    const float* F2w = (const float*)d_in[19]; const float* F2b = (const float*)d_in[20];
    (void)K1b; (void)K2b;   // kb terms cancel in softmax; K bias enters only via wvec

    float* out    = (float*)d_out;
    float* policy = out;                        // [512][64][16]
    float* w1     = out + 512 * 64 * 16;        // [4][512][64][64]
    float* w2     = w1 + 4 * 512 * 64 * 64;     // [4][512][64][64]

    // ws layout (shorts): x1b | xsb (states bf16; x2b aliases it after stage1) | wts | gt | wvec
    short* wsb = (short*)d_ws;
    short* x1b = wsb;                           // [512][64][128] = 4,194,304 shorts
    short* xsb = wsb + 4194304;                 // [512][64][256] = 8,388,608 shorts
    short* x2b = xsb;                           // alias: xsb dead once stage1 done
    short* wts = wsb + 12582912;
    short* wE1 = wts;                // [4][128][256] = 131072
    short* wV1 = wts + 131072;       // [4][32][128]  = 16384
    short* wE2 = wts + 147456;       // [4][128][128] = 65536
    short* wV2 = wts + 212992;       // 16384
    short* wF1 = wts + 229376;       // 8192
    short* wF2 = wts + 237568;       // 1024
    short* gt  = wts + 238592;       // [8][128][128] = 131072 shorts
    float* wvec = (float*)(wts + 238592 + 131072);  // [8][128] fp32

    ConvArgs ca;
    ca.src[0] = E1w; ca.src[1] = V1w; ca.src[2] = E2w; ca.src[3] = V2w;
    ca.src[4] = F1w; ca.src[5] = F2w; ca.src[6] = states;
    ca.end[0] = 32768;  ca.end[1] = 36864;  ca.end[2] = 53248;  ca.end[3] = 57344;
    ca.end[4] = 59392;  ca.end[5] = 59648;  ca.end[6] = 2156800;
    conv_and_gt_kernel<<<8937, 256, 0, stream>>>(ca, wts, xsb,
                                                 Q1w, K1w, Q1b, Q2w, K2w, Q2b, gt, wvec);

    attn_stage_kernel<256><<<1024, 512, 0, stream>>>(
        xsb, wE1, E1b, gt, wvec, wV1, V1b, w1, x1b);
    attn_stage_kernel<128><<<1024, 512, 0, stream>>>(
        x1b, wE2, E2b, gt + 65536, wvec + 512, wV2, V2b, w2, x2b);
    final_mlp_mfma_kernel<<<512, 256, 0, stream>>>(x2b, wF1, F1b, wF2, F2b, policy);
}

// Round 7
// 209.763 us; speedup vs baseline: 1.6763x; 1.0386x over previous
//
#include <hip/hip_runtime.h>

// ---------------- types / helpers ----------------
typedef __attribute__((ext_vector_type(8))) short short8;   // 8 bf16 = 4 VGPRs (MFMA A/B frag)
typedef __attribute__((ext_vector_type(4))) float f32x4;    // MFMA C/D frag
typedef __attribute__((ext_vector_type(2))) unsigned uint2v;

#define MFMA(a, b, c) __builtin_amdgcn_mfma_f32_16x16x32_bf16((a), (b), (c), 0, 0, 0)

__device__ __forceinline__ short f2bf(float f) {   // RNE float->bf16 (bit pattern as short)
    union { float f; unsigned u; } v; v.f = f;
    unsigned r = v.u + 0x7fffu + ((v.u >> 16) & 1u);
    return (short)(r >> 16);
}
__device__ __forceinline__ float bf2f(short s) {
    union { unsigned u; float f; } v; v.u = ((unsigned)(unsigned short)s) << 16; return v.f;
}
// pack two floats -> 2 bf16 in one u32 (pure integer ops; verified rounds 3-6)
__device__ __forceinline__ unsigned pkbf(float lo, float hi) {
    return (unsigned)(unsigned short)f2bf(lo) | ((unsigned)(unsigned short)f2bf(hi) << 16);
}
__device__ __forceinline__ float lrelu(float v) { return (v >= 0.f) ? v : 0.01f * v; }

// async global->LDS, 16B per lane; lds ptr wave-uniform (HW: base + lane*16)
__device__ __forceinline__ void load_lds16(const void* g, void* l) {
    __builtin_amdgcn_global_load_lds((const __attribute__((address_space(1))) void*)g,
                                     (__attribute__((address_space(3))) void*)l, 16, 0, 0);
}

// ---------------- merged: weights fp32->bf16 (233 blocks) + Gt/wvec precompute (512 blocks) ----------------
// Gt = (Qw^T Kw) * log2(e)/sqrt(d) bf16; wvec = (qb^T Kw) * log2(e)/sqrt(d) f32.
// log2(e) pre-folded so attn softmax can use exp2 (exp2(log2e*x) == e^x, exact same math).
struct ConvArgs { const float* src[6]; int end[6]; };  // end[] in float4 units, cumulative

__global__ __launch_bounds__(256) void conv_and_gt_kernel(ConvArgs a,
                                                          short* __restrict__ dstw,
                                                          const float* __restrict__ Q1w, const float* __restrict__ K1w,
                                                          const float* __restrict__ Q1b,
                                                          const float* __restrict__ Q2w, const float* __restrict__ K2w,
                                                          const float* __restrict__ Q2b,
                                                          short* __restrict__ gt, float* __restrict__ wvec) {
    if (blockIdx.x < 233) {
        int i4 = blockIdx.x * 256 + threadIdx.x;           // exactly 59,648 float4s
        int seg = 0;
#pragma unroll
        for (int s = 0; s < 5; s++) seg += (i4 >= a.end[s]) ? 1 : 0;
        int base = (seg == 0) ? 0 : a.end[seg - 1];
        float4 v = ((const float4*)a.src[seg])[i4 - base];
        uint2v o = { pkbf(v.x, v.y), pkbf(v.z, v.w) };
        *(uint2v*)(dstw + (size_t)i4 * 4) = o;
    } else {
        int bid = blockIdx.x - 233;                        // 0..511
        const int s  = bid >> 8;
        const int h  = (bid >> 6) & 3;
        const int fg = bid & 63;
        const float* Qw = (s ? Q2w : Q1w) + (size_t)h * 16384;
        const float* Kw = (s ? K2w : K1w) + (size_t)h * 16384;
        const float* qb = (s ? Q2b : Q1b) + h * 128;
        const int f = fg * 2 + (threadIdx.x >> 7);
        const int e = threadIdx.x & 127;
        float acc = 0.f, accw = 0.f;
#pragma unroll 8
        for (int c = 0; c < 128; c++) {
            float kv = Kw[c * 128 + f];
            acc  = fmaf(Qw[c * 128 + e], kv, acc);
            accw = fmaf(qb[c], kv, accw);
        }
        const float scale = 0.12751743f;                   // log2(e)/sqrt(128)
        gt[((size_t)((s * 4 + h) * 128 + f)) * 128 + e] = f2bf(acc * scale);
        if (e == 0) wvec[(s * 4 + h) * 128 + f] = accw * scale;
    }
}

// ---------------- fused attention stage: 2 heads/block, 8 waves, 2 blocks/CU (r6-verified) ----------------
// Waves 0-3 -> head h0, waves 4-7 -> head h0+1 (col-split within head).
// LDS (short offsets), total 38,400 shorts = 76,800 B -> 2 blocks/CU:
//   X  [64][IN] @0, padless, XOR-swizzled (16B chunks: LDS[r][c] = X[r][c^(r&7)]); dead after P1.
//   T  per-head [64][128] @ hsel*8192 (overlays X region; W overlays own T rows after logits)
//   SE per-head [64][136] @ 16384 + hsel*8704
//   VT per-head [32][72]  @ 33792 + hsel*2304
// wvec folded into T init => logits carry the column bias directly.
// XF32=true: stage X by converting fp32 on the fly (states path — no pre-conversion pass).
// XF32=false: stage X from bf16 global via global_load_lds (x1b path).
template<int IN, bool XF32>
__global__ __launch_bounds__(512, 4) void attn_stage_kernel(
    const void* __restrict__ xin,                       // [512][64][IN] fp32 (stage1) or bf16 (stage2)
    const short* __restrict__ Ew, const float* __restrict__ Eb,   // Ew bf16 [4][128][IN]
    const short* __restrict__ Gt, const float* __restrict__ wvec, // [4][128][128] bf16, [4][128] f32
    const short* __restrict__ Vw, const float* __restrict__ Vb,   // [4][32][128]
    float* __restrict__ w_out,                          // [4][512][64][64] fp32
    short* __restrict__ x_out)                          // [512][64][128] bf16
{
    __shared__ short sm[38400];

    const int tid  = threadIdx.x;
    // XCD-affinity: blocks b and b+512 (the two head-pairs of one b) share blockIdx%8 -> same XCD L2.
    const int b    = blockIdx.x & 511;
    const int h0   = (blockIdx.x >> 9) << 1;
    const int wv8  = tid >> 6;          // wave 0..7
    const int hsel = wv8 >> 2;
    const int wvl  = wv8 & 3;           // wave-in-head 0..3
    const int h    = h0 + hsel;
    const int lane = tid & 63;
    const int quad = lane >> 4;
    const int l16  = lane & 15;
    const int myrow = wvl * 16 + l16;
    const int OFF_T  = hsel * 8192;
    const int OFF_SE = 16384 + hsel * 8704;
    const int OFF_VT = 33792 + hsel * 2304;
    constexpr int NK1 = IN / 32;

    // ---- stage X into swizzled LDS layout: LDS[r][c] = X[r][c^(r&7)] (16B chunks) ----
    if constexpr (XF32) {
        // convert fp32 -> bf16 in-staging (removes the states pre-conversion pass entirely)
        const float* xb = (const float*)xin + (size_t)b * 64 * IN;
        constexpr int CPR = IN / 8;                        // 16B chunks per row
#pragma unroll
        for (int it = 0; it < 64 * CPR / 512; it++) {
            int idx = tid + 512 * it;                      // chunk index
            int row = idx / CPR, c = idx % CPR;
            const float* src = xb + row * IN + c * 8;      // 8 floats -> 8 bf16
            float4 a0 = *(const float4*)src;
            float4 a1 = *(const float4*)(src + 4);
            union { unsigned u[4]; short8 s; } o;
            o.u[0] = pkbf(a0.x, a0.y); o.u[1] = pkbf(a0.z, a0.w);
            o.u[2] = pkbf(a1.x, a1.y); o.u[3] = pkbf(a1.z, a1.w);
            *(short8*)&sm[row * IN + ((c ^ (row & 7)) << 3)] = o.s;
        }
    } else {
        // glds: pre-swizzled global source, linear LDS dest (r6-verified)
        const short* xg = (const short*)xin + (size_t)b * 64 * IN;
#pragma unroll
        for (int t = 0; t < IN / 64; t++) {
            int base  = wv8 * 8 * IN + t * 512;
            int off   = base + lane * 8;                   // short index this lane receives
            int row   = off / IN;
            int chunk = (off % IN) >> 3;
            int src   = row * IN + ((chunk ^ (row & 7)) << 3);
            load_lds16(xg + src, &sm[base]);
        }
    }

    // ---- prefetch phase-1 weight frags (A operand: Ew rows of head h) while staging in flight ----
    short8 ebf[NK1 * 2];
    {
        const short* ewh = Ew + (size_t)h * 128 * IN;
#pragma unroll
        for (int k0i = 0; k0i < NK1; k0i++)
#pragma unroll
            for (int j = 0; j < 2; j++)
                ebf[k0i * 2 + j] = *(const short8*)(ewh + (size_t)(wvl * 32 + j * 16 + l16) * IN + k0i * 32 + quad * 8);
    }
    __syncthreads();   // B1: X staged

    short8 gtf[8];   // G frags, prefetched during phase-1 epilogue
    short8 vbf[4];   // V-weight frags, also prefetched during phase-1 epilogue (hoisted from P2)
    const int n0v = (wvl >> 1) * 16, mrow = (wvl & 1) * 32;

    // ---- Phase 1 (swapped): C[e][n] = Ew x X^T; wave -> cols wvl*32..+31 of head h, all 64 rows ----
    {
        f32x4 acc[4][2];
#pragma unroll
        for (int j = 0; j < 2; j++) {
            f32x4 eb4 = *(const f32x4*)&Eb[h * 128 + wvl * 32 + j * 16 + quad * 4];
#pragma unroll
            for (int i = 0; i < 4; i++) acc[i][j] = eb4;
        }
        __builtin_amdgcn_s_setprio(1);
#pragma unroll
        for (int k0i = 0; k0i < NK1; k0i++) {
            short8 x8[4];
#pragma unroll
            for (int i = 0; i < 4; i++) {
                int xrow = i * 16 + l16;
                int kc = k0i * 4 + quad;
                x8[i] = *(const short8*)&sm[xrow * IN + ((kc ^ (xrow & 7)) << 3)];
            }
#pragma unroll
            for (int i = 0; i < 4; i++)
#pragma unroll
                for (int j = 0; j < 2; j++)
                    acc[i][j] = MFMA(ebf[k0i * 2 + j], x8[i], acc[i][j]);
        }
        __builtin_amdgcn_s_setprio(0);
        // hoisted prefetch: G + Vw frags fly during epilogue + barrier (ebf dead)
        {
            const short* gth = Gt + (size_t)h * 16384;
#pragma unroll
            for (int k0i = 0; k0i < 4; k0i++)
#pragma unroll
                for (int j = 0; j < 2; j++)
                    gtf[k0i * 2 + j] = *(const short8*)(gth + (size_t)(wvl * 32 + j * 16 + l16) * 128 + k0i * 32 + quad * 8);
            const short* vwh = Vw + (size_t)h * 32 * 128;
#pragma unroll
            for (int k0i = 0; k0i < 4; k0i++)
                vbf[k0i] = *(const short8*)(vwh + (size_t)(n0v + l16) * 128 + k0i * 32 + quad * 8);
        }
        // SE[n][e]: n = i*16+l16, e = wvl*32 + j*16 + quad*4 + r (contiguous)
#pragma unroll
        for (int i = 0; i < 4; i++)
#pragma unroll
            for (int j = 0; j < 2; j++) {
                uint2v o = { pkbf(lrelu(acc[i][j][0]), lrelu(acc[i][j][1])),
                             pkbf(lrelu(acc[i][j][2]), lrelu(acc[i][j][3])) };
                *(uint2v*)&sm[OFF_SE + (i * 16 + l16) * 136 + wvl * 32 + j * 16 + quad * 4] = o;
            }
    }
    __syncthreads();   // B2: SE (both heads) published; X dead (T overlays)

    // ---- Phase 2: T = SE @ G^T + wvec (bias-init); V ----
    {
        f32x4 tacc[4][2];
#pragma unroll
        for (int j = 0; j < 2; j++) {
            f32x4 wv4 = *(const f32x4*)&wvec[h * 128 + wvl * 32 + j * 16 + quad * 4];
#pragma unroll
            for (int i = 0; i < 4; i++) tacc[i][j] = wv4;
        }
        __builtin_amdgcn_s_setprio(1);
#pragma unroll
        for (int k0i = 0; k0i < 4; k0i++) {
            short8 se8[4];
#pragma unroll
            for (int i = 0; i < 4; i++)
                se8[i] = *(const short8*)&sm[OFF_SE + (i * 16 + l16) * 136 + k0i * 32 + quad * 8];
#pragma unroll
            for (int i = 0; i < 4; i++)
#pragma unroll
                for (int j = 0; j < 2; j++)
                    tacc[i][j] = MFMA(gtf[k0i * 2 + j], se8[i], tacc[i][j]);
        }
        // T[n][f] swizzled into head's T region: chunk c = (wvl*32+j*16+quad*4)>>3
#pragma unroll
        for (int i = 0; i < 4; i++)
#pragma unroll
            for (int j = 0; j < 2; j++) {
                uint2v ot = { pkbf(tacc[i][j][0], tacc[i][j][1]),
                              pkbf(tacc[i][j][2], tacc[i][j][3]) };
                int trow = i * 16 + l16;
                int c = wvl * 4 + j * 2 + (quad >> 1);
                *(uint2v*)&sm[OFF_T + trow * 128 + ((c ^ (trow & 7)) << 3) + (quad & 1) * 4] = ot;
            }

        // v = leaky(SE @ Vw^T + Vb): VT[o][n] (vbf already in regs)
        float vb = Vb[h * 32 + n0v + l16];
        f32x4 vacc[2];
        vacc[0] = (f32x4){vb, vb, vb, vb}; vacc[1] = vacc[0];
#pragma unroll
        for (int k0i = 0; k0i < 4; k0i++) {
            short8 a0 = *(const short8*)&sm[OFF_SE + (mrow + l16) * 136 + k0i * 32 + quad * 8];
            short8 a1 = *(const short8*)&sm[OFF_SE + (mrow + 16 + l16) * 136 + k0i * 32 + quad * 8];
            vacc[0] = MFMA(a0, vbf[k0i], vacc[0]);
            vacc[1] = MFMA(a1, vbf[k0i], vacc[1]);
        }
        __builtin_amdgcn_s_setprio(0);
#pragma unroll
        for (int i = 0; i < 2; i++) {
            uint2v ov = { pkbf(lrelu(vacc[i][0]), lrelu(vacc[i][1])),
                          pkbf(lrelu(vacc[i][2]), lrelu(vacc[i][3])) };
            *(uint2v*)&sm[OFF_VT + (n0v + l16) * 72 + mrow + i * 16 + quad * 4] = ov;
        }
    }
    __syncthreads();   // B3: T, VT published

    // ---- Phase 3 (swapped): C[k][q=myrow]; T frags via swizzled reads ----
    f32x4 lacc[4];
#pragma unroll
    for (int jj = 0; jj < 4; jj++) lacc[jj] = (f32x4){0.f, 0.f, 0.f, 0.f};
    __builtin_amdgcn_s_setprio(1);
#pragma unroll
    for (int k0 = 0; k0 < 128; k0 += 32) {
        int kc = (k0 >> 3) + quad;
        short8 tf = *(const short8*)&sm[OFF_T + myrow * 128 + ((kc ^ (myrow & 7)) << 3)];
#pragma unroll
        for (int jj = 0; jj < 4; jj++) {
            short8 af = *(const short8*)&sm[OFF_SE + (jj * 16 + l16) * 136 + k0 + quad * 8];
            lacc[jj] = MFMA(af, tf, lacc[jj]);
        }
    }
    __builtin_amdgcn_s_setprio(0);

    // ---- softmax (per-lane row; logits pre-scaled by log2e -> exp2); W overlays own T row ----
    {
        float m01 = fmaxf(fmaxf(lacc[0][0], lacc[0][1]), fmaxf(lacc[0][2], lacc[0][3]));
        float m23 = fmaxf(fmaxf(lacc[1][0], lacc[1][1]), fmaxf(lacc[1][2], lacc[1][3]));
        float m45 = fmaxf(fmaxf(lacc[2][0], lacc[2][1]), fmaxf(lacc[2][2], lacc[2][3]));
        float m67 = fmaxf(fmaxf(lacc[3][0], lacc[3][1]), fmaxf(lacc[3][2], lacc[3][3]));
        float m = fmaxf(fmaxf(m01, m23), fmaxf(m45, m67));
        m = fmaxf(m, __shfl_xor(m, 16, 64));
        m = fmaxf(m, __shfl_xor(m, 32, 64));
        float sum = 0.f;
#pragma unroll
        for (int jj = 0; jj < 4; jj++)
#pragma unroll
            for (int r = 0; r < 4; r++) {
                float e = exp2f(lacc[jj][r] - m);   // == e^(logit-max): log2e folded into Gt/wvec
                lacc[jj][r] = e; sum += e;
            }
        sum += __shfl_xor(sum, 16, 64);
        sum += __shfl_xor(sum, 32, 64);
        float inv = 1.0f / sum;
        float* wbase = w_out + ((size_t)(h * 512 + b)) * 4096 + (size_t)myrow * 64;
#pragma unroll
        for (int jj = 0; jj < 4; jj++) {
            f32x4 w4 = { lacc[jj][0] * inv, lacc[jj][1] * inv, lacc[jj][2] * inv, lacc[jj][3] * inv };
            uint2v o = { pkbf(w4[0], w4[1]), pkbf(w4[2], w4[3]) };
            int c = jj * 2 + (quad >> 1);
            *(uint2v*)&sm[OFF_T + myrow * 128 + ((c ^ (myrow & 7)) << 3) + (quad & 1) * 4] = o;
            __builtin_nontemporal_store(w4, (f32x4*)(wbase + jj * 16 + quad * 4));  // full 64B lines
        }
    }
    // no barrier: P4 reads VT (published B3) + own W row (same-wave ds ordering)

    // ---- Phase 4 (swapped): att C[o][q=myrow]; packed 8B x_out stores ----
    {
        f32x4 aacc[2]; aacc[0] = (f32x4){0.f, 0.f, 0.f, 0.f}; aacc[1] = aacc[0];
#pragma unroll
        for (int k0 = 0; k0 < 64; k0 += 32) {
            int kc = (k0 >> 3) + quad;
            short8 wf = *(const short8*)&sm[OFF_T + myrow * 128 + ((kc ^ (myrow & 7)) << 3)];
#pragma unroll
            for (int o = 0; o < 2; o++) {
                short8 vf = *(const short8*)&sm[OFF_VT + (o * 16 + l16) * 72 + k0 + quad * 8];
                aacc[o] = MFMA(vf, wf, aacc[o]);
            }
        }
        short* xob = x_out + (size_t)b * 8192 + (size_t)myrow * 128 + h * 32;
#pragma unroll
        for (int o = 0; o < 2; o++) {
            uint2v o8 = { pkbf(aacc[o][0], aacc[o][1]), pkbf(aacc[o][2], aacc[o][3]) };
            *(uint2v*)&xob[o * 16 + quad * 4] = o8;
        }
    }
}

// ---------------- final MLP + softmax (rounds 3-6 verified, unchanged) ----------------
#define H_LD 72
__global__ __launch_bounds__(256)
void final_mlp_mfma_kernel(const short* __restrict__ x2,    // [32768][128] bf16
                           const short* __restrict__ F1wb,  // [64][128] bf16
                           const float* __restrict__ F1b,   // [64]
                           const short* __restrict__ F2wb,  // [16][64] bf16
                           const float* __restrict__ F2b,   // [16]
                           float* __restrict__ policy)      // [32768][16]
{
    __shared__ short hsm[4][16 * H_LD];
    const int tid  = threadIdx.x;
    const int wv   = tid >> 6;
    const int lane = tid & 63;
    const int quad = lane >> 4;
    const int l16  = lane & 15;
    const int rowbase = blockIdx.x * 64 + wv * 16;

    short8 a[4];
    const short* xrow = x2 + (size_t)(rowbase + l16) * 128;
#pragma unroll
    for (int k = 0; k < 4; k++) a[k] = *(const short8*)(xrow + k * 32 + quad * 8);
    f32x4 acc[4];
#pragma unroll
    for (int j = 0; j < 4; j++) acc[j] = *(const f32x4*)&F1b[j * 16 + quad * 4];
#pragma unroll
    for (int k = 0; k < 4; k++)
#pragma unroll
        for (int j = 0; j < 4; j++) {
            short8 b8 = *(const short8*)(F1wb + (size_t)(j * 16 + l16) * 128 + k * 32 + quad * 8);
            acc[j] = MFMA(b8, a[k], acc[j]);
        }
    short* hh = &hsm[wv][0];
#pragma unroll
    for (int j = 0; j < 4; j++) {
        uint2v o = { pkbf(lrelu(acc[j][0]), lrelu(acc[j][1])),
                     pkbf(lrelu(acc[j][2]), lrelu(acc[j][3])) };
        *(uint2v*)&hh[l16 * H_LD + j * 16 + quad * 4] = o;
    }
    __syncthreads();

    f32x4 lg = *(const f32x4*)&F2b[quad * 4];
#pragma unroll
    for (int k = 0; k < 2; k++) {
        short8 a2 = *(const short8*)(hh + l16 * H_LD + k * 32 + quad * 8);
        short8 b2 = *(const short8*)(F2wb + (size_t)l16 * 64 + k * 32 + quad * 8);
        lg = MFMA(b2, a2, lg);
    }
    float m = fmaxf(fmaxf(lg[0], lg[1]), fmaxf(lg[2], lg[3]));
    m = fmaxf(m, __shfl_xor(m, 16, 64));
    m = fmaxf(m, __shfl_xor(m, 32, 64));
    f32x4 e;
    float s = 0.f;
#pragma unroll
    for (int r = 0; r < 4; r++) { e[r] = __expf(lg[r] - m); s += e[r]; }
    s += __shfl_xor(s, 16, 64);
    s += __shfl_xor(s, 32, 64);
    float inv = 1.0f / s;
    f32x4 p4 = { e[0] * inv, e[1] * inv, e[2] * inv, e[3] * inv };
    __builtin_nontemporal_store(p4, (f32x4*)&policy[(size_t)(rowbase + l16) * 16 + quad * 4]);
}

// ---------------- launcher ----------------
extern "C" void kernel_launch(void* const* d_in, const int* in_sizes, int n_in,
                              void* d_out, int out_size, void* d_ws, size_t ws_size,
                              hipStream_t stream) {
    const float* states = (const float*)d_in[0];
    const float* E1w = (const float*)d_in[1];  const float* E1b = (const float*)d_in[2];
    const float* K1w = (const float*)d_in[3];  const float* K1b = (const float*)d_in[4];
    const float* Q1w = (const float*)d_in[5];  const float* Q1b = (const float*)d_in[6];
    const float* V1w = (const float*)d_in[7];  const float* V1b = (const float*)d_in[8];
    const float* E2w = (const float*)d_in[9];  const float* E2b = (const float*)d_in[10];
    const float* K2w = (const float*)d_in[11]; const float* K2b = (const float*)d_in[12];
    const float* Q2w = (const float*)d_in[13]; const float* Q2b = (const float*)d_in[14];
    const float* V2w = (const float*)d_in[15]; const float* V2b = (const float*)d_in[16];
    const float* F1w = (const float*)d_in[17]; const float* F1b = (const float*)d_in[18];
    const float* F2w = (const float*)d_in[19]; const float* F2b = (const float*)d_in[20];
    (void)K1b; (void)K2b;   // kb terms cancel in softmax; K bias enters only via wvec

    float* out    = (float*)d_out;
    float* policy = out;                        // [512][64][16]
    float* w1     = out + 512 * 64 * 16;        // [4][512][64][64]
    float* w2     = w1 + 4 * 512 * 64 * 64;     // [4][512][64][64]

    // ws layout (shorts): x1b | x2b | bf16 weights | gt | wvec
    short* wsb = (short*)d_ws;
    short* x1b = wsb;                           // [512][64][128] = 4,194,304 shorts
    short* x2b = wsb + 4194304;                 // [512][64][128]
    short* wts = wsb + 8388608;
    short* wE1 = wts;                // [4][128][256] = 131072
    short* wV1 = wts + 131072;       // [4][32][128]  = 16384
    short* wE2 = wts + 147456;       // [4][128][128] = 65536
    short* wV2 = wts + 212992;       // 16384
    short* wF1 = wts + 229376;       // 8192
    short* wF2 = wts + 237568;       // 1024
    short* gt  = wts + 238592;       // [8][128][128] = 131072 shorts
    float* wvec = (float*)(wts + 238592 + 131072);  // [8][128] fp32

    ConvArgs ca;
    ca.src[0] = E1w; ca.src[1] = V1w; ca.src[2] = E2w; ca.src[3] = V2w;
    ca.src[4] = F1w; ca.src[5] = F2w;
    ca.end[0] = 32768;  ca.end[1] = 36864;  ca.end[2] = 53248;  ca.end[3] = 57344;
    ca.end[4] = 59392;  ca.end[5] = 59648;
    conv_and_gt_kernel<<<745, 256, 0, stream>>>(ca, wts,
                                                Q1w, K1w, Q1b, Q2w, K2w, Q2b, gt, wvec);

    attn_stage_kernel<256, true><<<1024, 512, 0, stream>>>(
        (const void*)states, wE1, E1b, gt, wvec, wV1, V1b, w1, x1b);
    attn_stage_kernel<128, false><<<1024, 512, 0, stream>>>(
        (const void*)x1b, wE2, E2b, gt + 65536, wvec + 512, wV2, V2b, w2, x2b);
    final_mlp_mfma_kernel<<<512, 256, 0, stream>>>(x2b, wF1, F1b, wF2, F2b, policy);
}